// Round 6
// baseline (36.628 us; speedup 1.0000x reference)
//
#include <hip/hip_runtime.h>
#include <hip/hip_bf16.h>

#define BATCH 16384
#define NCLS  1000
#define NPAD  1024
#define FDIM  512

// cbt layout per cblk: 16 slabs * 16KB ([chunk4][class256]x16B) + tail 4KB
#define CBLK_STRIDE 266240
#define TAIL_OFF    262144

typedef __bf16 bf16x4 __attribute__((ext_vector_type(4)));
typedef __bf16 bf16x8 __attribute__((ext_vector_type(8)));
typedef float  f32x16 __attribute__((ext_vector_type(16)));

#define GLOBAL_AS __attribute__((address_space(1)))
#define LDS_AS    __attribute__((address_space(3)))

#define VMCNT(n) asm volatile("s_waitcnt vmcnt(" #n ")" ::: "memory")
#define LGKM0()  asm volatile("s_waitcnt lgkmcnt(0)" ::: "memory")
#define BAR()    do { LGKM0(); __builtin_amdgcn_s_barrier(); \
                      __builtin_amdgcn_sched_barrier(0); } while (0)

// ---------------------------------------------------------------------------
// prep: centers fp32 [1000][512] -> cbt pre-tiled slab images; also zeroes
// out[0] (combine atomicAdds into it later on the same stream).
// ---------------------------------------------------------------------------
__global__ __launch_bounds__(64) void prep_centers(
    const float* __restrict__ centers, char* __restrict__ cbt,
    float* __restrict__ out)
{
    const int c = blockIdx.x, t = threadIdx.x;       // c 0..1023, t 0..63
    const int cblk = c >> 8, cl = c & 255;
    char* base = cbt + (size_t)cblk * CBLK_STRIDE;
    if (c == 0 && t == 0) out[0] = 0.f;

    float4 f0 = make_float4(0.f, 0.f, 0.f, 0.f);
    float4 f1 = make_float4(0.f, 0.f, 0.f, 0.f);
    if (c < NCLS) {
        f0 = *(const float4*)(centers + (size_t)c * FDIM + t * 8);
        f1 = *(const float4*)(centers + (size_t)c * FDIM + t * 8 + 4);
    }
    bf16x8 b;
    b[0] = (__bf16)f0.x; b[1] = (__bf16)f0.y; b[2] = (__bf16)f0.z; b[3] = (__bf16)f0.w;
    b[4] = (__bf16)f1.x; b[5] = (__bf16)f1.y; b[6] = (__bf16)f1.z; b[7] = (__bf16)f1.w;
    *(bf16x8*)(base + (t >> 2) * 16384 + (t & 3) * 4096 + cl * 16) = b;

    float ssum = f0.x*f0.x + f0.y*f0.y + f0.z*f0.z + f0.w*f0.w
               + f1.x*f1.x + f1.y*f1.y + f1.z*f1.z + f1.w*f1.w;
    #pragma unroll
    for (int o = 32; o > 0; o >>= 1) ssum += __shfl_down(ssum, o);
    if (t == 0) {
        const float hf = (c < NCLS) ? (-0.5f * ssum) : -1e30f;
        const __bf16 h = (__bf16)hf;
        const __bf16 l = (c < NCLS) ? (__bf16)(hf - (float)h) : (__bf16)0.f;
        bf16x8 tl;
        #pragma unroll
        for (int e = 0; e < 8; ++e) tl[e] = (__bf16)0.f;
        tl[0] = h; tl[1] = l;
        *(bf16x8*)(base + TAIL_OFF + cl * 16) = tl;
    }
}

// ---------------------------------------------------------------------------
// main: classes-as-M GEMM, acc[class][batch] = dot(c,x) - cn/2  (s = -2*acc)
//  block 256 cls x 256 batch, 4 waves (2M x 2N), wave 128x128 (4x4 frags).
//  grid = 4 cblk * 64 bblk = 256 blocks -> exactly 1/CU; XCD = bblk&7 so all
//  4 cblks of a bblk share one XCD's L2 (x fetched once per XCD).
//  BK=32, 16 slabs, triple-buffered, depth-2 prefetch, counted vmcnt(12).
//  A: cbt slab image -> contiguous memcpy via global_load_lds (4 instr/thr)
//  B: x fp32 reg-staged (8 coalesced dwordx4, named struct), cvt bf16,
//     8x ds_write_b64.   LDS: A 3x16K @0 | B 3x16K @48K | tail 4K @96K
// ---------------------------------------------------------------------------
struct B8 { float4 a, b, c, d, e, f, g, h; };

__global__ __launch_bounds__(256, 1) void trip_main(
    const float* __restrict__ x, const int* __restrict__ labels,
    const char* __restrict__ cbt, float* __restrict__ mxp,
    float* __restrict__ dap)
{
    extern __shared__ char lds[];
    const int t    = threadIdx.x;
    const int lane = t & 63;
    const int w    = t >> 6;          // 0..3
    const int wN   = w & 1, wM = w >> 1;
    const int l31  = lane & 31, hi = lane >> 5;
    const int bid  = blockIdx.x;
    const int cblk = bid >> 6;        // 0..3
    const int bblk = bid & 63;        // 0..63 -> XCD = bblk & 7
    const int class0 = cblk * 256;
    const int row0   = bblk * 256;
    const char* cbB  = cbt + (size_t)cblk * CBLK_STRIDE;

    auto stageA = [&](int ko, int ai) {   // 16KB contiguous memcpy, 4 instr
        const char* src = cbB + ko * 16384 + w * 4096 + lane * 16;
        char* dst = lds + ai * 16384 + w * 4096 + lane * 16;
        #pragma unroll
        for (int j = 0; j < 4; ++j)
            __builtin_amdgcn_global_load_lds(
                (const GLOBAL_AS void*)(src + j * 1024),
                (LDS_AS void*)(dst + j * 1024), 16, 0, 0);
    };
    auto loadB = [&](int ko, B8& br) {    // 8 dwordx4, 8 full lines each
        const float* src = x + (size_t)row0 * FDIM + ko * 32
                         + (size_t)(w * 64 + (lane >> 3)) * FDIM + (lane & 7) * 4;
        br.a = *(const float4*)(src);
        br.b = *(const float4*)(src +  8 * FDIM);
        br.c = *(const float4*)(src + 16 * FDIM);
        br.d = *(const float4*)(src + 24 * FDIM);
        br.e = *(const float4*)(src + 32 * FDIM);
        br.f = *(const float4*)(src + 40 * FDIM);
        br.g = *(const float4*)(src + 48 * FDIM);
        br.h = *(const float4*)(src + 56 * FDIM);
    };
    auto cv4 = [](float4 f) {
        bf16x4 v;
        v[0] = (__bf16)f.x; v[1] = (__bf16)f.y;
        v[2] = (__bf16)f.z; v[3] = (__bf16)f.w;
        return v;
    };
    auto writeB = [&](const B8& br, int bi) {   // 8 ds_write_b64
        char* dst = lds + 49152 + bi * 16384 + ((lane & 7) >> 1) * 4096
                  + (w * 64 + (lane >> 3)) * 16 + (lane & 1) * 8;
        *(bf16x4*)(dst      ) = cv4(br.a);
        *(bf16x4*)(dst + 128) = cv4(br.b);
        *(bf16x4*)(dst + 256) = cv4(br.c);
        *(bf16x4*)(dst + 384) = cv4(br.d);
        *(bf16x4*)(dst + 512) = cv4(br.e);
        *(bf16x4*)(dst + 640) = cv4(br.f);
        *(bf16x4*)(dst + 768) = cv4(br.g);
        *(bf16x4*)(dst + 896) = cv4(br.h);
    };

    f32x16 acc[4][4];
    #pragma unroll
    for (int mi = 0; mi < 4; ++mi)
        #pragma unroll
        for (int ni = 0; ni < 4; ++ni)
            #pragma unroll
            for (int r = 0; r < 16; ++r) acc[mi][ni][r] = 0.f;

    auto compute = [&](int buf) {
        const char* A = lds + buf * 16384;
        const char* B = lds + 49152 + buf * 16384;
        #pragma unroll
        for (int ks = 0; ks < 2; ++ks) {
            const int chunk = ks * 2 + hi;
            bf16x8 a[4], b[4];
            #pragma unroll
            for (int mi = 0; mi < 4; ++mi)
                a[mi] = *(const bf16x8*)(A + chunk * 4096 + (wM * 128 + mi * 32 + l31) * 16);
            #pragma unroll
            for (int ni = 0; ni < 4; ++ni)
                b[ni] = *(const bf16x8*)(B + chunk * 4096 + (wN * 128 + ni * 32 + l31) * 16);
            #pragma unroll
            for (int mi = 0; mi < 4; ++mi)
                #pragma unroll
                for (int ni = 0; ni < 4; ++ni)
                    acc[mi][ni] = __builtin_amdgcn_mfma_f32_32x32x16_bf16(
                        a[mi], b[ni], acc[mi][ni], 0, 0, 0);
        }
    };

    // ---- prologue (ledger: lab 4, tail 1, A0 4, B0 8 | A1 4, B1 8) ----
    const int lab0 = labels[row0 + wN * 128 +  0 + l31];
    const int lab1 = labels[row0 + wN * 128 + 32 + l31];
    const int lab2 = labels[row0 + wN * 128 + 64 + l31];
    const int lab3 = labels[row0 + wN * 128 + 96 + l31];
    {   // tail A: 4KB contiguous memcpy (1 instr/thread)
        const char* src = cbB + TAIL_OFF + t * 16;
        char* dst = lds + 98304 + t * 16;
        __builtin_amdgcn_global_load_lds((const GLOBAL_AS void*)src,
                                         (LDS_AS void*)dst, 16, 0, 0);
    }
    B8 brA, brB;
    stageA(0, 0); loadB(0, brA);
    __builtin_amdgcn_sched_barrier(0);   // pin: {lab,tail,A0,B0} before {A1,B1}
    stageA(1, 1); loadB(1, brB);
    VMCNT(12);           // drain lab+tail+slab0; keep slab1's 12 in flight
    writeB(brA, 0);
    BAR();

    // ---- K pipeline: 16 slabs of 32, FULLY UNROLLED ----
    #pragma unroll
    for (int tt = 0; tt < 16; ++tt) {
        const int cur = tt % 3, wr = (tt + 1) % 3, pre = (tt + 2) % 3;
        if (tt < 14) {
            stageA(tt + 2, pre);
            if (tt & 1) loadB(tt + 2, brB);
            else        loadB(tt + 2, brA);
            VMCNT(12);   // drain slab tt+1 (A DMA + B regs); keep tt+2's 12
        } else {
            VMCNT(0);
        }
        if (tt < 15) {
            if (tt & 1) writeB(brA, wr);
            else        writeB(brB, wr);
        }
        compute(cur);
        BAR();
    }

    // ---- tail k-step (k 512..527): A from tail LDS, B = (1,1,0,...) ----
    {
        const char* T = lds + 98304;
        bf16x8 bt;
        #pragma unroll
        for (int e = 0; e < 8; ++e) bt[e] = (__bf16)0.f;
        if (hi == 0) { bt[0] = (__bf16)1.0f; bt[1] = (__bf16)1.0f; }
        #pragma unroll
        for (int mi = 0; mi < 4; ++mi) {
            bf16x8 a = *(const bf16x8*)(T + (wM * 128 + mi * 32 + l31) * 16);
            #pragma unroll
            for (int ni = 0; ni < 4; ++ni)
                acc[mi][ni] = __builtin_amdgcn_mfma_f32_32x32x16_bf16(
                    a, bt, acc[mi][ni], 0, 0, 0);
        }
    }

    // ---- epilogue: per-lane max over non-label classes + label acc ----
    const int labBase = class0 + wM * 128 + hi * 4;
    const int lA0 = lab0 - labBase, lA1 = lab1 - labBase;
    const int lA2 = lab2 - labBase, lA3 = lab3 - labBase;
    float MX0 = -3e38f, MX1 = -3e38f, MX2 = -3e38f, MX3 = -3e38f;
    float DA0 = -3e38f, DA1 = -3e38f, DA2 = -3e38f, DA3 = -3e38f;
    #pragma unroll
    for (int mi = 0; mi < 4; ++mi) {
        #pragma unroll
        for (int r = 0; r < 16; ++r) {
            const int pat = mi * 32 + (r & 3) + 8 * (r >> 2);
            { const float a = acc[mi][0][r]; const bool is = (lA0 == pat);
              MX0 = fmaxf(MX0, is ? -3e38f : a); DA0 = is ? a : DA0; }
            { const float a = acc[mi][1][r]; const bool is = (lA1 == pat);
              MX1 = fmaxf(MX1, is ? -3e38f : a); DA1 = is ? a : DA1; }
            { const float a = acc[mi][2][r]; const bool is = (lA2 == pat);
              MX2 = fmaxf(MX2, is ? -3e38f : a); DA2 = is ? a : DA2; }
            { const float a = acc[mi][3][r]; const bool is = (lA3 == pat);
              MX3 = fmaxf(MX3, is ? -3e38f : a); DA3 = is ? a : DA3; }
        }
    }
    MX0 = fmaxf(MX0, __shfl_xor(MX0, 32)); DA0 = fmaxf(DA0, __shfl_xor(DA0, 32));
    MX1 = fmaxf(MX1, __shfl_xor(MX1, 32)); DA1 = fmaxf(DA1, __shfl_xor(DA1, 32));
    MX2 = fmaxf(MX2, __shfl_xor(MX2, 32)); DA2 = fmaxf(DA2, __shfl_xor(DA2, 32));
    MX3 = fmaxf(MX3, __shfl_xor(MX3, 32)); DA3 = fmaxf(DA3, __shfl_xor(DA3, 32));

    // ---- merge the two M-waves via scratch (reuse A buf0), store ----
    float* sc = (float*)lds;              // [256] MX, [256] DA
    const int i0 = wN * 128 +  0 + l31;
    const int i1 = wN * 128 + 32 + l31;
    const int i2 = wN * 128 + 64 + l31;
    const int i3 = wN * 128 + 96 + l31;
    if (wM == 1 && hi == 0) {
        sc[i0] = MX0; sc[256 + i0] = DA0;
        sc[i1] = MX1; sc[256 + i1] = DA1;
        sc[i2] = MX2; sc[256 + i2] = DA2;
        sc[i3] = MX3; sc[256 + i3] = DA3;
    }
    __syncthreads();
    if (wM == 0 && hi == 0) {
        const int rg = row0 + wN * 128 + l31;
        mxp[cblk * BATCH + rg     ] = fmaxf(MX0, sc[i0]);
        dap[cblk * BATCH + rg     ] = fmaxf(DA0, sc[256 + i0]);
        mxp[cblk * BATCH + rg + 32] = fmaxf(MX1, sc[i1]);
        dap[cblk * BATCH + rg + 32] = fmaxf(DA1, sc[256 + i1]);
        mxp[cblk * BATCH + rg + 64] = fmaxf(MX2, sc[i2]);
        dap[cblk * BATCH + rg + 64] = fmaxf(DA2, sc[256 + i2]);
        mxp[cblk * BATCH + rg + 96] = fmaxf(MX3, sc[i3]);
        dap[cblk * BATCH + rg + 96] = fmaxf(DA3, sc[256 + i3]);
    }
}

// ---------------------------------------------------------------------------
// combine: fold 4 cblk partials, hinge, block-sum, one atomicAdd per block.
// out[0] zeroed by prep_centers (stream-ordered before this kernel).
// ---------------------------------------------------------------------------
__global__ __launch_bounds__(256) void combine(
    const float* __restrict__ mxp, const float* __restrict__ dap,
    const float* __restrict__ margin, float* __restrict__ out)
{
    const int t = threadIdx.x;
    const int row = blockIdx.x * 256 + t;
    float mx = fmaxf(fmaxf(mxp[row], mxp[BATCH + row]),
                     fmaxf(mxp[2 * BATCH + row], mxp[3 * BATCH + row]));
    float da = fmaxf(fmaxf(dap[row], dap[BATCH + row]),
                     fmaxf(dap[2 * BATCH + row], dap[3 * BATCH + row]));
    // dist = -2*da, dist_min = -2*mx
    float loss = fmaxf(margin[0] - 2.f * da + 2.f * mx, 0.f);
    __shared__ float red[4];
    #pragma unroll
    for (int o = 32; o > 0; o >>= 1) loss += __shfl_down(loss, o);
    if ((t & 63) == 0) red[t >> 6] = loss;
    __syncthreads();
    if (t == 0)
        atomicAdd(out, (red[0] + red[1] + red[2] + red[3]) * (1.0f / BATCH));
}

// ---------------------------------------------------------------------------
extern "C" void kernel_launch(void* const* d_in, const int* in_sizes, int n_in,
                              void* d_out, int out_size, void* d_ws, size_t ws_size,
                              hipStream_t stream)
{
    const float* x       = (const float*)d_in[0];
    const int*   labels  = (const int*)d_in[1];
    const float* centers = (const float*)d_in[2];
    const float* margin  = (const float*)d_in[3];
    float* out = (float*)d_out;

    char* ws = (char*)d_ws;
    char*  cbt  = ws;                                  // 1,064,960 B
    float* mxp  = (float*)(ws + 1064960);              //   262,144 B
    float* dap  = (float*)(ws + 1327104);              //   262,144 B

    (void)hipFuncSetAttribute((const void*)trip_main,
                              hipFuncAttributeMaxDynamicSharedMemorySize, 102400);

    prep_centers<<<NPAD, 64, 0, stream>>>(centers, cbt, out);
    trip_main<<<256, 256, 102400, stream>>>(x, labels, cbt, mxp, dap);
    combine<<<64, 256, 0, stream>>>(mxp, dap, margin, out);
}

// Round 7
// 33.952 us; speedup vs baseline: 1.0788x; 1.0788x over previous
//
#include <hip/hip_runtime.h>
#include <hip/hip_bf16.h>

#define BATCH 16384
#define NCLS  1000
#define NPAD  1024
#define FDIM  512

// cbt layout per cblk: 8 slabs * 32KB ([chunk8][class256]x16B) + tail 4KB
#define CBLK_STRIDE 266240
#define TAIL_OFF    262144

typedef __bf16 bf16x4 __attribute__((ext_vector_type(4)));
typedef __bf16 bf16x8 __attribute__((ext_vector_type(8)));
typedef float  f32x16 __attribute__((ext_vector_type(16)));

#define GLOBAL_AS __attribute__((address_space(1)))
#define LDS_AS    __attribute__((address_space(3)))

#define VMCNT(n) asm volatile("s_waitcnt vmcnt(" #n ")" ::: "memory")
#define LGKM0()  asm volatile("s_waitcnt lgkmcnt(0)" ::: "memory")
#define BAR()    do { LGKM0(); __builtin_amdgcn_s_barrier(); \
                      __builtin_amdgcn_sched_barrier(0); } while (0)

// ---------------------------------------------------------------------------
// prep: centers fp32 [1000][512] -> cbt pre-tiled BK=64 slab images; zeroes
// out[0] (combine atomicAdds into it on the same stream).
// thread t owns 8-k chunk t: slab t>>3, in-slab chunk t&7.
// ---------------------------------------------------------------------------
__global__ __launch_bounds__(64) void prep_centers(
    const float* __restrict__ centers, char* __restrict__ cbt,
    float* __restrict__ out)
{
    const int c = blockIdx.x, t = threadIdx.x;       // c 0..1023, t 0..63
    const int cblk = c >> 8, cl = c & 255;
    char* base = cbt + (size_t)cblk * CBLK_STRIDE;
    if (c == 0 && t == 0) out[0] = 0.f;

    float4 f0 = make_float4(0.f, 0.f, 0.f, 0.f);
    float4 f1 = make_float4(0.f, 0.f, 0.f, 0.f);
    if (c < NCLS) {
        f0 = *(const float4*)(centers + (size_t)c * FDIM + t * 8);
        f1 = *(const float4*)(centers + (size_t)c * FDIM + t * 8 + 4);
    }
    bf16x8 b;
    b[0] = (__bf16)f0.x; b[1] = (__bf16)f0.y; b[2] = (__bf16)f0.z; b[3] = (__bf16)f0.w;
    b[4] = (__bf16)f1.x; b[5] = (__bf16)f1.y; b[6] = (__bf16)f1.z; b[7] = (__bf16)f1.w;
    *(bf16x8*)(base + (t >> 3) * 32768 + (t & 7) * 4096 + cl * 16) = b;

    float ssum = f0.x*f0.x + f0.y*f0.y + f0.z*f0.z + f0.w*f0.w
               + f1.x*f1.x + f1.y*f1.y + f1.z*f1.z + f1.w*f1.w;
    #pragma unroll
    for (int o = 32; o > 0; o >>= 1) ssum += __shfl_down(ssum, o);
    if (t == 0) {
        const float hf = (c < NCLS) ? (-0.5f * ssum) : -1e30f;
        const __bf16 h = (__bf16)hf;
        const __bf16 l = (c < NCLS) ? (__bf16)(hf - (float)h) : (__bf16)0.f;
        bf16x8 tl;
        #pragma unroll
        for (int e = 0; e < 8; ++e) tl[e] = (__bf16)0.f;
        tl[0] = h; tl[1] = l;
        *(bf16x8*)(base + TAIL_OFF + cl * 16) = tl;
    }
}

// ---------------------------------------------------------------------------
// main: classes-as-M GEMM, acc[class][batch] = dot(c,x) - cn/2  (s = -2*acc)
//  block 256 cls x 256 batch, 8 waves (2M x 4N), wave 128x64 (4x2 frags).
//  grid = 4 cblk * 64 bblk = 256 -> 1/CU, 2 waves/SIMD; XCD = bid&7 = bblk&7
//  so all 4 cblks of a bblk share one XCD's L2.
//  BK=64, 8 slabs, DOUBLE-buffered, depth-1 A / depth-2 B, counted vmcnt(12):
//  half the barrier/drain events of BK=32, 32 MFMA per barrier per wave.
//  A: cbt slab image -> contiguous memcpy via global_load_lds (4 instr/thr)
//  B: x fp32 reg-staged (8 coalesced dwordx4, named structs), cvt bf16,
//     8x ds_write_b64.  LDS: A 2x32K @0 | B 2x32K @64K | tail 4K @128K
// ---------------------------------------------------------------------------
struct B8 { float4 a, b, c, d, e, f, g, h; };

__global__ __launch_bounds__(512, 1) void trip_main(
    const float* __restrict__ x, const int* __restrict__ labels,
    const char* __restrict__ cbt, float* __restrict__ mxp,
    float* __restrict__ dap)
{
    extern __shared__ char lds[];
    const int t    = threadIdx.x;
    const int lane = t & 63;
    const int w    = t >> 6;          // 0..7
    const int wN   = w & 3, wM = w >> 2;
    const int l31  = lane & 31, hi = lane >> 5;
    const int bid  = blockIdx.x;
    const int cblk = bid >> 6;        // 0..3
    const int bblk = bid & 63;        // 0..63 -> XCD = bblk & 7
    const int class0 = cblk * 256;
    const int row0   = bblk * 256;
    const char* cbB  = cbt + (size_t)cblk * CBLK_STRIDE;

    auto stageA = [&](int ko, int ai) {   // 32KB contiguous memcpy, 4 instr
        const char* src = cbB + ko * 32768 + t * 16;
        char* dst = lds + ai * 32768 + t * 16;
        #pragma unroll
        for (int j = 0; j < 4; ++j)
            __builtin_amdgcn_global_load_lds(
                (const GLOBAL_AS void*)(src + j * 8192),
                (LDS_AS void*)(dst + j * 8192), 16, 0, 0);
    };
    auto loadB = [&](int ko, B8& br) {    // 8 dwordx4, fully-used lines
        const float* src = x + (size_t)(row0 + w * 32 + (lane >> 3)) * FDIM
                         + ko * 64 + (lane & 7) * 4;
        br.a = *(const float4*)(src);                    // j=0: rows +0, k lo
        br.b = *(const float4*)(src + 32);               // j=1: rows +0, k hi
        br.c = *(const float4*)(src +  8 * FDIM);        // j=2: rows +8, k lo
        br.d = *(const float4*)(src +  8 * FDIM + 32);
        br.e = *(const float4*)(src + 16 * FDIM);
        br.f = *(const float4*)(src + 16 * FDIM + 32);
        br.g = *(const float4*)(src + 24 * FDIM);
        br.h = *(const float4*)(src + 24 * FDIM + 32);
    };
    auto cv4 = [](float4 f) {
        bf16x4 v;
        v[0] = (__bf16)f.x; v[1] = (__bf16)f.y;
        v[2] = (__bf16)f.z; v[3] = (__bf16)f.w;
        return v;
    };
    auto writeB = [&](const B8& br, int bi) {   // 8 ds_write_b64
        // cell: chunk = khalf*4 + ((lane&7)>>1), row, half = lane&1
        char* dst = lds + 65536 + bi * 32768 + ((lane & 7) >> 1) * 4096
                  + (w * 32 + (lane >> 3)) * 16 + (lane & 1) * 8;
        *(bf16x4*)(dst              ) = cv4(br.a);   // rows+0, chunks 0-3
        *(bf16x4*)(dst + 4 * 4096   ) = cv4(br.b);   // rows+0, chunks 4-7
        *(bf16x4*)(dst + 128        ) = cv4(br.c);   // rows+8
        *(bf16x4*)(dst + 4 * 4096 + 128) = cv4(br.d);
        *(bf16x4*)(dst + 256        ) = cv4(br.e);   // rows+16
        *(bf16x4*)(dst + 4 * 4096 + 256) = cv4(br.f);
        *(bf16x4*)(dst + 384        ) = cv4(br.g);   // rows+24
        *(bf16x4*)(dst + 4 * 4096 + 384) = cv4(br.h);
    };

    f32x16 acc[4][2];
    #pragma unroll
    for (int mi = 0; mi < 4; ++mi)
        #pragma unroll
        for (int ni = 0; ni < 2; ++ni)
            #pragma unroll
            for (int r = 0; r < 16; ++r) acc[mi][ni][r] = 0.f;

    auto compute = [&](int buf) {
        const char* A = lds + buf * 32768;
        const char* B = lds + 65536 + buf * 32768;
        #pragma unroll
        for (int ks = 0; ks < 4; ++ks) {
            const int chunk = ks * 2 + hi;
            bf16x8 a[4], b[2];
            #pragma unroll
            for (int mi = 0; mi < 4; ++mi)
                a[mi] = *(const bf16x8*)(A + chunk * 4096 + (wM * 128 + mi * 32 + l31) * 16);
            #pragma unroll
            for (int ni = 0; ni < 2; ++ni)
                b[ni] = *(const bf16x8*)(B + chunk * 4096 + (wN * 64 + ni * 32 + l31) * 16);
            #pragma unroll
            for (int mi = 0; mi < 4; ++mi)
                #pragma unroll
                for (int ni = 0; ni < 2; ++ni)
                    acc[mi][ni] = __builtin_amdgcn_mfma_f32_32x32x16_bf16(
                        a[mi], b[ni], acc[mi][ni], 0, 0, 0);
        }
    };

    // ---- prologue (ledger: lab 2, tail <=1, A0 4, B0 8 | B1 8, A1 4) ----
    const int lab0 = labels[row0 + wN * 64 + l31];
    const int lab1 = labels[row0 + wN * 64 + 32 + l31];
    if (t < 256) {   // tail A: 4KB contiguous memcpy (waves 0-3 only)
        const char* src = cbB + TAIL_OFF + t * 16;
        char* dst = lds + 131072 + t * 16;
        __builtin_amdgcn_global_load_lds((const GLOBAL_AS void*)src,
                                         (LDS_AS void*)dst, 16, 0, 0);
    }
    B8 brA, brB;
    stageA(0, 0); loadB(0, brA);
    __builtin_amdgcn_sched_barrier(0);   // pin: {lab,tail,A0,B0} first
    loadB(1, brB); stageA(1, 1);
    VMCNT(12);           // drain lab+tail+A0+B0; keep B1(8)+A1(4)
    writeB(brA, 0);
    BAR();

    // ---- K pipeline: 8 slabs of 64, FULLY UNROLLED, 1 barrier/slab ----
    #pragma unroll
    for (int tt = 0; tt < 8; ++tt) {
        if (tt >= 1 && tt <= 6) stageA(tt + 1, (tt + 1) & 1);
        if (tt <= 5) {
            if (tt & 1) loadB(tt + 2, brB);
            else        loadB(tt + 2, brA);
        }
        if (tt <= 5)      VMCNT(12);  // drain {A(tt),B(tt+1)}; keep 12
        else if (tt == 6) VMCNT(4);   // keep A7 only
        else              VMCNT(0);
        if (tt <= 6) {
            if (tt & 1) writeB(brA, (tt + 1) & 1);
            else        writeB(brB, (tt + 1) & 1);
        }
        compute(tt & 1);
        BAR();
    }

    // ---- tail k-step (k 512..527): A from tail LDS, B = (1,1,0,...) ----
    {
        const char* T = lds + 131072;
        bf16x8 bt;
        #pragma unroll
        for (int e = 0; e < 8; ++e) bt[e] = (__bf16)0.f;
        if (hi == 0) { bt[0] = (__bf16)1.0f; bt[1] = (__bf16)1.0f; }
        #pragma unroll
        for (int mi = 0; mi < 4; ++mi) {
            bf16x8 a = *(const bf16x8*)(T + (wM * 128 + mi * 32 + l31) * 16);
            #pragma unroll
            for (int ni = 0; ni < 2; ++ni)
                acc[mi][ni] = __builtin_amdgcn_mfma_f32_32x32x16_bf16(
                    a, bt, acc[mi][ni], 0, 0, 0);
        }
    }

    // ---- epilogue: per-lane max over non-label classes + label acc ----
    const int labBase = class0 + wM * 128 + hi * 4;
    const int labA0 = lab0 - labBase;
    const int labA1 = lab1 - labBase;
    float MX0 = -3e38f, MX1 = -3e38f, DA0 = -3e38f, DA1 = -3e38f;
    #pragma unroll
    for (int mi = 0; mi < 4; ++mi) {
        #pragma unroll
        for (int r = 0; r < 16; ++r) {
            const int pat = mi * 32 + (r & 3) + 8 * (r >> 2);
            {
                const float a = acc[mi][0][r];
                const bool is = (labA0 == pat);
                MX0 = fmaxf(MX0, is ? -3e38f : a);
                DA0 = is ? a : DA0;
            }
            {
                const float a = acc[mi][1][r];
                const bool is = (labA1 == pat);
                MX1 = fmaxf(MX1, is ? -3e38f : a);
                DA1 = is ? a : DA1;
            }
        }
    }
    MX0 = fmaxf(MX0, __shfl_xor(MX0, 32));
    DA0 = fmaxf(DA0, __shfl_xor(DA0, 32));
    MX1 = fmaxf(MX1, __shfl_xor(MX1, 32));
    DA1 = fmaxf(DA1, __shfl_xor(DA1, 32));

    // ---- merge the two M-waves via scratch (B buf0, retired), store ----
    float* sc = (float*)(lds + 65536);    // [256] MX, [256] DA
    const int i0 = (wN * 2 + 0) * 32 + l31;
    const int i1 = (wN * 2 + 1) * 32 + l31;
    if (wM == 1 && hi == 0) {
        sc[i0] = MX0; sc[256 + i0] = DA0;
        sc[i1] = MX1; sc[256 + i1] = DA1;
    }
    __syncthreads();
    if (wM == 0 && hi == 0) {
        const float M0 = fmaxf(MX0, sc[i0]),  D0 = fmaxf(DA0, sc[256 + i0]);
        const float M1 = fmaxf(MX1, sc[i1]),  D1 = fmaxf(DA1, sc[256 + i1]);
        const int rg = row0 + wN * 64 + l31;
        mxp[cblk * BATCH + rg]      = M0;
        dap[cblk * BATCH + rg]      = D0;
        mxp[cblk * BATCH + rg + 32] = M1;
        dap[cblk * BATCH + rg + 32] = D1;
    }
}

// ---------------------------------------------------------------------------
// combine: fold 4 cblk partials, hinge, block-sum, one atomicAdd per block.
// out[0] zeroed by prep_centers (stream-ordered before this kernel).
// ---------------------------------------------------------------------------
__global__ __launch_bounds__(256) void combine(
    const float* __restrict__ mxp, const float* __restrict__ dap,
    const float* __restrict__ margin, float* __restrict__ out)
{
    const int t = threadIdx.x;
    const int row = blockIdx.x * 256 + t;
    float mx = fmaxf(fmaxf(mxp[row], mxp[BATCH + row]),
                     fmaxf(mxp[2 * BATCH + row], mxp[3 * BATCH + row]));
    float da = fmaxf(fmaxf(dap[row], dap[BATCH + row]),
                     fmaxf(dap[2 * BATCH + row], dap[3 * BATCH + row]));
    // dist = -2*da, dist_min = -2*mx
    float loss = fmaxf(margin[0] - 2.f * da + 2.f * mx, 0.f);
    __shared__ float red[4];
    #pragma unroll
    for (int o = 32; o > 0; o >>= 1) loss += __shfl_down(loss, o);
    if ((t & 63) == 0) red[t >> 6] = loss;
    __syncthreads();
    if (t == 0)
        atomicAdd(out, (red[0] + red[1] + red[2] + red[3]) * (1.0f / BATCH));
}

// ---------------------------------------------------------------------------
extern "C" void kernel_launch(void* const* d_in, const int* in_sizes, int n_in,
                              void* d_out, int out_size, void* d_ws, size_t ws_size,
                              hipStream_t stream)
{
    const float* x       = (const float*)d_in[0];
    const int*   labels  = (const int*)d_in[1];
    const float* centers = (const float*)d_in[2];
    const float* margin  = (const float*)d_in[3];
    float* out = (float*)d_out;

    char* ws = (char*)d_ws;
    char*  cbt  = ws;                                  // 1,064,960 B
    float* mxp  = (float*)(ws + 1064960);              //   262,144 B
    float* dap  = (float*)(ws + 1327104);              //   262,144 B

    (void)hipFuncSetAttribute((const void*)trip_main,
                              hipFuncAttributeMaxDynamicSharedMemorySize, 135168);

    prep_centers<<<NPAD, 64, 0, stream>>>(centers, cbt, out);
    trip_main<<<256, 512, 135168, stream>>>(x, labels, cbt, mxp, dap);
    combine<<<64, 256, 0, stream>>>(mxp, dap, margin, out);
}